// Round 10
// baseline (214.890 us; speedup 1.0000x reference)
//
#include <hip/hip_runtime.h>
#include <hip/hip_bf16.h>
#include <math.h>

// Problem constants
#define S_LEN   2048
#define BATCH   2
#define DMODEL  1024
#define NHEADS  16
#define DKH     64
#define MROWS   (BATCH * S_LEN)   // 4096

// attn split-KV geometry (R19, measured-best): QBLK=64, KVBLK=32.
// qb 0..16 single block; qb 17..31 two halves. Pieces/bh = 47; partial
// slots/bh = 30 -> 960 slots x (64x64 o + 64 l) fp32 in d_out.
#define SPLIT_Q0   17
#define NPIECE     47
#define SLOTS_BH   30
#define PO_FLOATS  (960 * 4096)

typedef __attribute__((ext_vector_type(8)))  __bf16 bf16x8;
typedef __attribute__((ext_vector_type(4)))  float  f32x4;
typedef __attribute__((ext_vector_type(16))) float  f32x16;
typedef __attribute__((ext_vector_type(8)))  unsigned short u16x8;
typedef __attribute__((ext_vector_type(2)))  unsigned int   u32x2;

__device__ __forceinline__ float bfu2f(unsigned short u) {
    union { unsigned int i; float f; } v;
    v.i = ((unsigned int)u) << 16;
    return v.f;
}

__device__ __forceinline__ unsigned short f2bfu(float f) {
    union { __bf16 h; unsigned short u; } v;
    v.h = (__bf16)f;    // native RNE cvt
    return v.u;
}

#define LGKM0() __builtin_amdgcn_s_waitcnt(0xc07f)   // lgkmcnt(0), vmcnt free

// counted-vmcnt + raw barrier (T4)
#define VMCNT_BAR(n) do {                                        \
    asm volatile("s_waitcnt vmcnt(" #n ")" ::: "memory");        \
    __builtin_amdgcn_s_barrier();                                \
    __builtin_amdgcn_sched_barrier(0);                           \
} while (0)

// global -> LDS direct DMA, 16B per lane
__device__ __forceinline__ void gload_lds16(const void* g, void* l) {
    __builtin_amdgcn_global_load_lds(
        (const __attribute__((address_space(1))) void*)g,
        (__attribute__((address_space(3))) void*)l, 16, 0, 0);
}

// ---------------------------------------------------------------------------
// Pre-convert: Wq/Wk/Wv -> bf16 (ws) and x -> bf16 (d_out scratch).
// ---------------------------------------------------------------------------
__global__ __launch_bounds__(256) void cvt_all(
    const float* __restrict__ W0, const float* __restrict__ W1, const float* __restrict__ W2,
    const float* __restrict__ X,
    unsigned short* __restrict__ Wb, unsigned short* __restrict__ Xb)
{
    const int y = blockIdx.y;
    const float* src;
    unsigned short* dst;
    if (y < 3) {
        src = (y == 0) ? W0 : (y == 1) ? W1 : W2;
        dst = Wb + (size_t)y * (DMODEL * DMODEL);
    } else {
        src = X + (size_t)(y - 3) * (DMODEL * DMODEL);
        dst = Xb + (size_t)(y - 3) * (DMODEL * DMODEL);
    }
    size_t idx = ((size_t)blockIdx.x * 256 + threadIdx.x) * 8;
    float4 a = *(const float4*)(src + idx);
    float4 b = *(const float4*)(src + idx + 4);
    u16x8 h;
    h[0] = f2bfu(a.x); h[1] = f2bfu(a.y); h[2] = f2bfu(a.z); h[3] = f2bfu(a.w);
    h[4] = f2bfu(b.x); h[5] = f2bfu(b.y); h[6] = f2bfu(b.z); h[7] = f2bfu(b.w);
    *(u16x8*)(dst + idx) = h;
}

// ---------------------------------------------------------------------------
// QKV MFMA GEMM (R16, measured-best): 3-buffer counted-vmcnt. Unchanged.
// ---------------------------------------------------------------------------
__global__ __launch_bounds__(256) void gemm_qkv(
    const unsigned short* __restrict__ Xb,
    const unsigned short* __restrict__ Wb,
    unsigned short* __restrict__ Yq, unsigned short* __restrict__ Yk, unsigned short* __restrict__ Yv)
{
    __shared__ __align__(16) unsigned char pool[49152];
    unsigned short* base = (unsigned short*)pool;

    const int tid  = threadIdx.x;
    const int wave = tid >> 6;
    const int lane = tid & 63;
    const int c    = lane & 15;
    const int quad = lane >> 4;

    const int m0 = blockIdx.y * 128;
    const int n0 = blockIdx.x * 128;
    const int w_idx = n0 >> 10;
    const int e0    = n0 & 1023;
    const unsigned short* Wsrc = Wb + (size_t)w_idx * (DMODEL * DMODEL);

    const int mhalf = (wave & 1) * 64;
    const int nhalf = (wave >> 1) * 64;

    f32x4 acc[4][4];
#pragma unroll
    for (int i = 0; i < 4; i++)
#pragma unroll
        for (int j = 0; j < 4; j++) acc[i][j] = (f32x4){0.f, 0.f, 0.f, 0.f};

    const int srow = wave * 32 + (lane >> 2);
    const int scol = (lane & 3) * 8;
    const unsigned short* Asrc = Xb   + (size_t)(m0 + srow) * DMODEL + scol;
    const unsigned short* Bsrc = Wsrc + (size_t)(e0 + srow) * DMODEL + scol;
    const int doff = srow * 32 + scol;

#define QKV_STAGE(buf, kt) do {                                                    \
    unsigned short* _A = base + (buf) * 8192;                                      \
    unsigned short* _B = _A + 4096;                                                \
    const int _k0 = (kt) * 32;                                                     \
    _Pragma("unroll")                                                              \
    for (int _j = 0; _j < 2; _j++) {                                               \
        gload_lds16(Asrc + (size_t)(_j * 16) * DMODEL + _k0, _A + doff + _j * 512);\
        gload_lds16(Bsrc + (size_t)(_j * 16) * DMODEL + _k0, _B + doff + _j * 512);\
    }                                                                              \
} while (0)

#define QKV_COMPUTE(buf) do {                                                      \
    const unsigned short* _A = base + (buf) * 8192;                                \
    const unsigned short* _B = _A + 4096;                                          \
    bf16x8 af[4], bfr[4];                                                          \
    _Pragma("unroll")                                                              \
    for (int mt = 0; mt < 4; mt++)                                                 \
        af[mt] = *(const bf16x8*)(&_A[(mhalf + mt * 16 + c) * 32 + quad * 8]);     \
    _Pragma("unroll")                                                              \
    for (int nt = 0; nt < 4; nt++)                                                 \
        bfr[nt] = *(const bf16x8*)(&_B[(nhalf + nt * 16 + c) * 32 + quad * 8]);    \
    _Pragma("unroll")                                                              \
    for (int mt = 0; mt < 4; mt++)                                                 \
        _Pragma("unroll")                                                          \
        for (int nt = 0; nt < 4; nt++)                                             \
            acc[mt][nt] = __builtin_amdgcn_mfma_f32_16x16x32_bf16(af[mt], bfr[nt], acc[mt][nt], 0, 0, 0); \
} while (0)

    QKV_STAGE(0, 0);
    QKV_STAGE(1, 1);
    for (int g = 0; g < 10; ++g) {
        const int t = g * 3;
        VMCNT_BAR(4); QKV_STAGE(2, t + 2); QKV_COMPUTE(0);
        VMCNT_BAR(4); QKV_STAGE(0, t + 3); QKV_COMPUTE(1);
        VMCNT_BAR(4); QKV_STAGE(1, t + 4); QKV_COMPUTE(2);
    }
    VMCNT_BAR(4); QKV_COMPUTE(0);
    VMCNT_BAR(0); QKV_COMPUTE(1);

    __syncthreads();

    const int h = (e0 + nhalf) >> 6;
    if (w_idx < 2) {
        unsigned short* Yqk = (w_idx == 0) ? Yq : Yk;
        float* EPf = (float*)pool + wave * 16 * 68;
        const int row = lane >> 2;
        const int cg  = lane & 3;
#pragma unroll
        for (int mt = 0; mt < 4; mt++) {
            LGKM0();
#pragma unroll
            for (int nt = 0; nt < 4; nt++)
#pragma unroll
                for (int r = 0; r < 4; r++)
                    EPf[(quad * 4 + r) * 68 + nt * 16 + c] = acc[mt][nt][r];
            LGKM0();
            float fl[16];
#pragma unroll
            for (int j = 0; j < 4; j++) {
                float4 v = *(const float4*)(&EPf[row * 68 + cg * 16 + j * 4]);
                fl[j * 4 + 0] = v.x; fl[j * 4 + 1] = v.y;
                fl[j * 4 + 2] = v.z; fl[j * 4 + 3] = v.w;
            }
            int m = m0 + mhalf + mt * 16 + row;
            int s = m & (S_LEN - 1);
            int b = m >> 11;
            u16x8 o0, o1;
#pragma unroll
            for (int pi = 0; pi < 8; pi++) {
                int p = cg * 8 + pi;
                float freq  = exp2f(-(float)p * 0.41524101186092034f);
                float angle = (float)s * freq;
                float sn, cs;
                __sincosf(angle, &sn, &cs);
                float ev = fl[2 * pi], ov = fl[2 * pi + 1];
                float re = ev * cs - ov * sn;
                float ro = ev * sn + ov * cs;
                if (pi < 4) { o0[2 * pi] = f2bfu(re); o0[2 * pi + 1] = f2bfu(ro); }
                else        { o1[2 * (pi - 4)] = f2bfu(re); o1[2 * (pi - 4) + 1] = f2bfu(ro); }
            }
            unsigned short* dst = Yqk + (((size_t)(b * NHEADS + h)) * S_LEN + s) * DKH + cg * 16;
            *(u16x8*)(dst)     = o0;
            *(u16x8*)(dst + 8) = o1;
        }
    } else {
        unsigned short* EPb = (unsigned short*)pool + wave * 64 * 72;
        LGKM0();
#pragma unroll
        for (int nt = 0; nt < 4; nt++)
#pragma unroll
            for (int mt = 0; mt < 4; mt++)
#pragma unroll
                for (int r = 0; r < 4; r++)
                    EPb[(nt * 16 + c) * 72 + mt * 16 + quad * 4 + r] = f2bfu(acc[mt][nt][r]);
        LGKM0();
        int mbase = m0 + mhalf;
        int s0 = mbase & (S_LEN - 1);
        int b  = mbase >> 11;
        unsigned short* dst = Yv + (((size_t)(b * NHEADS + h)) * DKH + lane) * S_LEN + s0;
#pragma unroll
        for (int j = 0; j < 8; j++)
            *(u16x8*)(dst + j * 8) = *(const u16x8*)(&EPb[lane * 72 + j * 8]);
    }
#undef QKV_STAGE
#undef QKV_COMPUTE
}

// ---------------------------------------------------------------------------
// Wo MFMA GEMM (R16, kept). Unchanged.
// ---------------------------------------------------------------------------
__global__ __launch_bounds__(256) void gemm_wo(
    const unsigned short* __restrict__ X,
    const unsigned short* __restrict__ Wob,
    float* __restrict__ Yf)
{
    __shared__ __align__(16) unsigned char pool[36864];
    unsigned short* base = (unsigned short*)pool;

    const int tid  = threadIdx.x;
    const int wave = tid >> 6;
    const int lane = tid & 63;
    const int c    = lane & 15;
    const int quad = lane >> 4;

    const int m0 = blockIdx.y * 64;
    const int n0 = blockIdx.x * 128;

    const int mhalf = (wave & 1) * 32;
    const int nhalf = (wave >> 1) * 64;

    f32x4 acc[2][4];
#pragma unroll
    for (int i = 0; i < 2; i++)
#pragma unroll
        for (int j = 0; j < 4; j++) acc[i][j] = (f32x4){0.f, 0.f, 0.f, 0.f};

    const int arow = wave * 16 + (lane >> 2);
    const int brow = wave * 32 + (lane >> 2);
    const int scol = (lane & 3) * 8;
    const unsigned short* Asrc = X   + (size_t)(m0 + arow) * DMODEL + scol;
    const unsigned short* Bsrc = Wob + (size_t)(n0 + brow) * DMODEL + scol;
    const int adoff = arow * 32 + scol;
    const int bdoff = brow * 32 + scol;

#define WO_STAGE(buf, kt) do {                                                     \
    unsigned short* _A = base + (buf) * 6144;                                      \
    unsigned short* _B = _A + 2048;                                                \
    const int _k0 = (kt) * 32;                                                     \
    gload_lds16(Asrc + _k0, _A + adoff);                                           \
    _Pragma("unroll")                                                              \
    for (int _j = 0; _j < 2; _j++)                                                 \
        gload_lds16(Bsrc + (size_t)(_j * 16) * DMODEL + _k0, _B + bdoff + _j * 512);\
} while (0)

#define WO_COMPUTE(buf) do {                                                       \
    const unsigned short* _A = base + (buf) * 6144;                                \
    const unsigned short* _B = _A + 2048;                                          \
    bf16x8 af[2], bfr[4];                                                          \
    _Pragma("unroll")                                                              \
    for (int mt = 0; mt < 2; mt++)                                                 \
        af[mt] = *(const bf16x8*)(&_A[(mhalf + mt * 16 + c) * 32 + quad * 8]);     \
    _Pragma("unroll")                                                              \
    for (int nt = 0; nt < 4; nt++)                                                 \
        bfr[nt] = *(const bf16x8*)(&_B[(nhalf + nt * 16 + c) * 32 + quad * 8]);    \
    _Pragma("unroll")                                                              \
    for (int mt = 0; mt < 2; mt++)                                                 \
        _Pragma("unroll")                                                          \
        for (int nt = 0; nt < 4; nt++)                                             \
            acc[mt][nt] = __builtin_amdgcn_mfma_f32_16x16x32_bf16(af[mt], bfr[nt], acc[mt][nt], 0, 0, 0); \
} while (0)

    WO_STAGE(0, 0);
    WO_STAGE(1, 1);
    for (int g = 0; g < 10; ++g) {
        const int t = g * 3;
        VMCNT_BAR(3); WO_STAGE(2, t + 2); WO_COMPUTE(0);
        VMCNT_BAR(3); WO_STAGE(0, t + 3); WO_COMPUTE(1);
        VMCNT_BAR(3); WO_STAGE(1, t + 4); WO_COMPUTE(2);
    }
    VMCNT_BAR(3); WO_COMPUTE(0);
    VMCNT_BAR(0); WO_COMPUTE(1);

    __syncthreads();

    float* EPf = (float*)pool + wave * 16 * 68;
    const int row = lane >> 2;
    const int cg  = lane & 3;
#pragma unroll
    for (int mt = 0; mt < 2; mt++) {
        LGKM0();
#pragma unroll
        for (int nt = 0; nt < 4; nt++)
#pragma unroll
            for (int r = 0; r < 4; r++)
                EPf[(quad * 4 + r) * 68 + nt * 16 + c] = acc[mt][nt][r];
        LGKM0();
        int m = m0 + mhalf + mt * 16 + row;
        float* dst = Yf + (size_t)m * DMODEL + n0 + nhalf + cg * 16;
#pragma unroll
        for (int j = 0; j < 4; j++)
            *(float4*)(dst + j * 4) = *(const float4*)(&EPf[row * 68 + cg * 16 + j * 4]);
    }
#undef WO_STAGE
#undef WO_COMPUTE
}

// ---------------------------------------------------------------------------
// MFMA flash attention R22: R21 math + ZERO barriers, zero shared staging.
// Theory: K/V per bh = 512KB, 4 bh/XCD = 2MB -> fully L2-resident (HBM 6%).
// Guide common-mistake #7 / m169: staging L2-fit data is pure overhead.
//  - K fragments read DIRECT from global (K-tile is 4KB contiguous; frag
//    loads pair lanes into 32B segments -> L2-friendly).
//  - V kept in a WAVE-PRIVATE LDS buffer (single-buffered): global V-tile
//    read is the coalesced 64-row x 64B pattern into regs (T14 prefetch of
//    tile kb+1 issued before compute), ds_write AFTER PV consumed the
//    current tile's reads (same-wave DS dependency; LDS aliasing stops
//    reordering). No __syncthreads anywhere.
//  - Waves clip their loop to their causal limit (w_hi = min(t_hi,my_nkb)):
//    the staging-only idle iterations of R19 disappear (~13% fewer iters).
// LDS 10.2KB/block; (128,4) -> 8 blocks/CU co-residency cap (was ~4-6).
// Piece mapping / split slots / epilogue identical to verified R19/R21.
// ---------------------------------------------------------------------------
__global__ __launch_bounds__(128, 4) void attn_mfma(
    const unsigned short* __restrict__ Q,
    const unsigned short* __restrict__ K,
    const unsigned short* __restrict__ Vt,
    unsigned short* __restrict__ A,
    float* __restrict__ Scr)
{
    __shared__ __align__(16) unsigned short Vs[2][64 * 40];   // per-WAVE private

    const int tid  = threadIdx.x;
    const int wave = tid >> 6;    // 0..1
    const int lane = tid & 63;
    const int c32  = lane & 31;
    const int hi   = lane >> 5;

    const int bh = blockIdx.x;
    const int b  = bh >> 4;
    const int h  = bh & 15;

    // Piece mapping (identical to R18/R19/R21)
    const int R = (int)blockIdx.y;
    int qb, t_lo, t_hi, spl = 0;
    bool is_split;
    if (R <= 16) {
        qb = 16 - R; t_lo = 0; t_hi = 2 * qb + 2; is_split = false;
    } else {
        int i = R - 17;
        qb  = 31 - (i >> 1);
        spl = i & 1;
        int nk = 2 * qb + 2, half = nk >> 1;
        t_lo = spl ? half : 0;
        t_hi = spl ? nk   : half;
        is_split = true;
    }
    const int q0b = qb * 64;
    const int q0w = q0b + wave * 32;

    const unsigned short* Qb = Q  + (size_t)bh * S_LEN * DKH;
    const unsigned short* Kb = K  + (size_t)bh * S_LEN * DKH;
    const unsigned short* Vb = Vt + (size_t)bh * DKH * S_LEN;

    // Q B-frags: lane holds Q[q = q0w+c32][dk = t*16 + hi*8 + 0..7]
    bf16x8 qf0 = *(const bf16x8*)(Qb + (size_t)(q0w + c32) * DKH +  0 + hi * 8);
    bf16x8 qf1 = *(const bf16x8*)(Qb + (size_t)(q0w + c32) * DKH + 16 + hi * 8);
    bf16x8 qf2 = *(const bf16x8*)(Qb + (size_t)(q0w + c32) * DKH + 32 + hi * 8);
    bf16x8 qf3 = *(const bf16x8*)(Qb + (size_t)(q0w + c32) * DKH + 48 + hi * 8);

    f32x16 oA, oB;
#pragma unroll
    for (int r = 0; r < 16; r++) { oA[r] = 0.f; oB[r] = 0.f; }
    float lacc = 0.f;

    const int my_nkb = (q0w >> 5) + 1;           // causal tile limit
    const int kbf    = q0w >> 5;                 // tiles < kbf are mask-free
    const int w_hi   = (t_hi < my_nkb) ? t_hi : my_nkb;

    // V staging: lane = dv row; 64B (4 x uint4) per tile per lane.
    unsigned short* Vw = &Vs[wave][0];
    const unsigned short* Vrow = Vb + (size_t)lane * S_LEN;

    uint4 gv0, gv1, gv2, gv3;
    if (t_lo < w_hi) {
        const unsigned short* vp = Vrow + t_lo * 32;
        gv0 = *(const uint4*)(vp);      gv1 = *(const uint4*)(vp + 8);
        gv2 = *(const uint4*)(vp + 16); gv3 = *(const uint4*)(vp + 24);
        *(uint4*)(&Vw[lane * 40 +  0]) = gv0;
        *(uint4*)(&Vw[lane * 40 +  8]) = gv1;
        *(uint4*)(&Vw[lane * 40 + 16]) = gv2;
        *(uint4*)(&Vw[lane * 40 + 24]) = gv3;
    }

    for (int kb = t_lo; kb < w_hi; kb++) {
        const int k0 = kb * 32;
        const bool pre = (kb + 1) < w_hi;

        // K fragments DIRECT from global (L2-resident; 4KB contiguous tile)
        const unsigned short* Kp = Kb + (size_t)(k0 + c32) * DKH + hi * 8;
        bf16x8 kf0 = *(const bf16x8*)(Kp);
        bf16x8 kf1 = *(const bf16x8*)(Kp + 16);
        bf16x8 kf2 = *(const bf16x8*)(Kp + 32);
        bf16x8 kf3 = *(const bf16x8*)(Kp + 48);

        if (pre) {   // T14: prefetch next V tile into regs now, write late
            const unsigned short* vp = Vrow + (kb + 1) * 32;
            gv0 = *(const uint4*)(vp);      gv1 = *(const uint4*)(vp + 8);
            gv2 = *(const uint4*)(vp + 16); gv3 = *(const uint4*)(vp + 24);
        }

        f32x16 s;
#pragma unroll
        for (int r = 0; r < 16; r++) s[r] = 0.f;
        __builtin_amdgcn_s_setprio(1);
        s = __builtin_amdgcn_mfma_f32_32x32x16_bf16(kf0, qf0, s, 0, 0, 0);
        s = __builtin_amdgcn_mfma_f32_32x32x16_bf16(kf1, qf1, s, 0, 0, 0);
        s = __builtin_amdgcn_mfma_f32_32x32x16_bf16(kf2, qf2, s, 0, 0, 0);
        s = __builtin_amdgcn_mfma_f32_32x32x16_bf16(kf3, qf3, s, 0, 0, 0);
        __builtin_amdgcn_s_setprio(0);
        // s[r] = S[key = k0 + (r&3)+8*(r>>2)+4*hi][q = q0w + c32]
        float p[16];
        if (kb < kbf) {
#pragma unroll
            for (int r = 0; r < 16; r++) p[r] = __expf(s[r] * 0.125f);
        } else {
            const int qg = q0w + c32;
#pragma unroll
            for (int r = 0; r < 16; r++) {
                int kg = k0 + (r & 3) + 8 * (r >> 2) + 4 * hi;
                p[r] = (kg <= qg) ? __expf(s[r] * 0.125f) : 0.0f;
            }
        }
        // pack to bf16 pairs; accumulate l from ROUNDED values
        unsigned pk[8];
#pragma unroll
        for (int i = 0; i < 8; i++) {
            asm("v_cvt_pk_bf16_f32 %0, %1, %2"
                : "=v"(pk[i]) : "v"(p[2 * i]), "v"(p[2 * i + 1]));
            union { unsigned u; float f; } lo, hx;
            lo.u = pk[i] << 16;
            hx.u = pk[i] & 0xffff0000u;
            lacc += lo.f + hx.f;
        }
        // key-half exchange via permlane32_swap (verified R21)
        u32x2 s02 = __builtin_amdgcn_permlane32_swap(pk[0], pk[2], false, false);
        u32x2 s13 = __builtin_amdgcn_permlane32_swap(pk[1], pk[3], false, false);
        u32x2 s46 = __builtin_amdgcn_permlane32_swap(pk[4], pk[6], false, false);
        u32x2 s57 = __builtin_amdgcn_permlane32_swap(pk[5], pk[7], false, false);
        union { unsigned u[4]; bf16x8 v; } pa0, pa1;
        pa0.u[0] = s02[0]; pa0.u[1] = s13[0]; pa0.u[2] = s02[1]; pa0.u[3] = s13[1];
        pa1.u[0] = s46[0]; pa1.u[1] = s57[0]; pa1.u[2] = s46[1]; pa1.u[3] = s57[1];
        // V fragments from the wave-private buffer
        bf16x8 v00 = *(const bf16x8*)(&Vw[(c32)      * 40 +  0 + hi * 8]);
        bf16x8 v10 = *(const bf16x8*)(&Vw[(c32)      * 40 + 16 + hi * 8]);
        bf16x8 v01 = *(const bf16x8*)(&Vw[(32 + c32) * 40 +  0 + hi * 8]);
        bf16x8 v11 = *(const bf16x8*)(&Vw[(32 + c32) * 40 + 16 + hi * 8]);
        __builtin_amdgcn_s_setprio(1);
        oA = __builtin_amdgcn_mfma_f32_32x32x16_bf16(pa0.v, v00, oA, 0, 0, 0);
        oA = __builtin_amdgcn_mfma_f32_32x32x16_bf16(pa1.v, v10, oA, 0, 0, 0);
        oB = __builtin_amdgcn_mfma_f32_32x32x16_bf16(pa0.v, v01, oB, 0, 0, 0);
        oB = __builtin_amdgcn_mfma_f32_32x32x16_bf16(pa1.v, v11, oB, 0, 0, 0);
        __builtin_amdgcn_s_setprio(0);

        if (pre) {   // write next V tile AFTER PV consumed current reads
            *(uint4*)(&Vw[lane * 40 +  0]) = gv0;
            *(uint4*)(&Vw[lane * 40 +  8]) = gv1;
            *(uint4*)(&Vw[lane * 40 + 16]) = gv2;
            *(uint4*)(&Vw[lane * 40 + 24]) = gv3;
        }
    }

    // combine halves: full l for q = q0w + c32 at every lane
    lacc += __shfl_xor(lacc, 32, 64);

    if (!is_split) {
        float inv = 1.0f / lacc;
#pragma unroll
        for (int r = 0; r < 16; r++) {
            int qr = (r & 3) + 8 * (r >> 2) + 4 * hi;   // output q-row of reg r
            float invr = __shfl(inv, qr, 64);
            int sg = q0w + qr;
            unsigned short* Ap = A + ((size_t)b * S_LEN + sg) * DMODEL + h * DKH;
            Ap[c32]      = f2bfu(oA[r] * invr);
            Ap[32 + c32] = f2bfu(oB[r] * invr);
        }
    } else {
        const int slot = bh * SLOTS_BH + (qb - SPLIT_Q0) * 2 + spl;
        float* Po = Scr + (size_t)slot * 4096;
        float* Pl = Scr + PO_FLOATS + (size_t)slot * 64;
#pragma unroll
        for (int r = 0; r < 16; r++) {
            int qr  = (r & 3) + 8 * (r >> 2) + 4 * hi;
            int row = wave * 32 + qr;
            Po[row * 64 + c32]      = oA[r];
            Po[row * 64 + 32 + c32] = oB[r];
        }
        if (hi == 0) Pl[wave * 32 + c32] = lacc;
    }
}

// ---------------------------------------------------------------------------
// Merged combine + Wo-convert (saves one launch): blocks [0,480) combine
// split partials A = (o0+o1)/(l0+l1); blocks [480,992) convert Wo -> bf16.
// ---------------------------------------------------------------------------
__global__ __launch_bounds__(256) void combine_cvtwo(
    const float* __restrict__ Scr, unsigned short* __restrict__ A,
    const float* __restrict__ Wo, unsigned short* __restrict__ Wob)
{
    if (blockIdx.x >= 480) {
        size_t idx = ((size_t)(blockIdx.x - 480) * 256 + threadIdx.x) * 8;
        float4 a = *(const float4*)(Wo + idx);
        float4 b = *(const float4*)(Wo + idx + 4);
        u16x8 hh;
        hh[0] = f2bfu(a.x); hh[1] = f2bfu(a.y); hh[2] = f2bfu(a.z); hh[3] = f2bfu(a.w);
        hh[4] = f2bfu(b.x); hh[5] = f2bfu(b.y); hh[6] = f2bfu(b.z); hh[7] = f2bfu(b.w);
        *(u16x8*)(Wob + idx) = hh;
        return;
    }
    const int bx  = blockIdx.x;
    const int bh  = bx / 15;
    const int qbm = bx % 15;
    const int qb  = SPLIT_Q0 + qbm;
    const int b   = bh >> 4;
    const int h   = bh & 15;

    const int slot0 = bh * SLOTS_BH + qbm * 2;
    const float* O0 = Scr + (size_t)slot0 * 4096;
    const float* O1 = O0 + 4096;
    const float* L0 = Scr + PO_FLOATS + (size_t)slot0 * 64;
    const float* L1 = L0 + 64;

    const int r  = threadIdx.x >> 2;
    const int cg = (threadIdx.x & 3) * 16;

    float inv = 1.0f / (L0[r] + L1[r]);

    u16x8 outv[2];
#pragma unroll
    for (int half = 0; half < 2; half++) {
        float4 a0 = *(const float4*)(O0 + r * 64 + cg + half * 8);
        float4 b0 = *(const float4*)(O0 + r * 64 + cg + half * 8 + 4);
        float4 a1 = *(const float4*)(O1 + r * 64 + cg + half * 8);
        float4 b1 = *(const float4*)(O1 + r * 64 + cg + half * 8 + 4);
        outv[half][0] = f2bfu((a0.x + a1.x) * inv);
        outv[half][1] = f2bfu((a0.y + a1.y) * inv);
        outv[half][2] = f2bfu((a0.z + a1.z) * inv);
        outv[half][3] = f2bfu((a0.w + a1.w) * inv);
        outv[half][4] = f2bfu((b0.x + b1.x) * inv);
        outv[half][5] = f2bfu((b0.y + b1.y) * inv);
        outv[half][6] = f2bfu((b0.z + b1.z) * inv);
        outv[half][7] = f2bfu((b0.w + b1.w) * inv);
    }
    const int s = qb * 64 + r;
    unsigned short* Ap = A + ((size_t)b * S_LEN + s) * DMODEL + h * DKH + cg;
    *(u16x8*)(Ap)     = outv[0];
    *(u16x8*)(Ap + 8) = outv[1];
}

extern "C" void kernel_launch(void* const* d_in, const int* in_sizes, int n_in,
                              void* d_out, int out_size, void* d_ws, size_t ws_size,
                              hipStream_t stream) {
    const float* x  = (const float*)d_in[0];
    const float* Wq = (const float*)d_in[1];
    const float* Wk = (const float*)d_in[2];
    const float* Wv = (const float*)d_in[3];
    const float* Wo = (const float*)d_in[4];
    float* out = (float*)d_out;

    unsigned short* Qw = (unsigned short*)d_ws;
    unsigned short* Kw = Qw + (size_t)MROWS * DMODEL;
    unsigned short* Vw = Kw + (size_t)MROWS * DMODEL;
    unsigned short* Wb = Vw + (size_t)MROWS * DMODEL;
    unsigned short* Aw = Wb;    // aliased; QKV completes before attn writes A
    unsigned short* Wob = Qw;   // aliased; Q dead after attn_mfma
    unsigned short* Xb = (unsigned short*)d_out;
    float* Scr = (float*)d_out;

    cvt_all<<<dim3(DMODEL * DMODEL / (256 * 8), 7), 256, 0, stream>>>(Wq, Wk, Wv, x, Wb, Xb);

    gemm_qkv<<<dim3(3 * DMODEL / 128, MROWS / 128), 256, 0, stream>>>(
        Xb, Wb, Qw, Kw, Vw);

    attn_mfma<<<dim3(NHEADS * BATCH, NPIECE), 128, 0, stream>>>(Qw, Kw, Vw, Aw, Scr);

    combine_cvtwo<<<dim3(480 + 512), 256, 0, stream>>>(Scr, Aw, Wo, Wob);

    gemm_wo<<<dim3(DMODEL / 128, MROWS / 64), 256, 0, stream>>>(Aw, Wob, out);
}

// Round 11
// 181.852 us; speedup vs baseline: 1.1817x; 1.1817x over previous
//
#include <hip/hip_runtime.h>
#include <hip/hip_bf16.h>
#include <math.h>

// Problem constants
#define S_LEN   2048
#define BATCH   2
#define DMODEL  1024
#define NHEADS  16
#define DKH     64
#define MROWS   (BATCH * S_LEN)   // 4096

// attn split-KV geometry (R19/R21, measured-best): QBLK=64, KVBLK=32.
#define SPLIT_Q0   17
#define NPIECE     47
#define SLOTS_BH   30
#define PO_FLOATS  (960 * 4096)

typedef __attribute__((ext_vector_type(8)))  __bf16 bf16x8;
typedef __attribute__((ext_vector_type(4)))  float  f32x4;
typedef __attribute__((ext_vector_type(16))) float  f32x16;
typedef __attribute__((ext_vector_type(8)))  unsigned short u16x8;
typedef __attribute__((ext_vector_type(2)))  unsigned int   u32x2;

__device__ __forceinline__ float bfu2f(unsigned short u) {
    union { unsigned int i; float f; } v;
    v.i = ((unsigned int)u) << 16;
    return v.f;
}

__device__ __forceinline__ unsigned short f2bfu(float f) {
    union { __bf16 h; unsigned short u; } v;
    v.h = (__bf16)f;    // native RNE cvt
    return v.u;
}

#define LGKM0() __builtin_amdgcn_s_waitcnt(0xc07f)   // lgkmcnt(0), vmcnt free

// counted-vmcnt + raw barrier (T4)
#define VMCNT_BAR(n) do {                                        \
    asm volatile("s_waitcnt vmcnt(" #n ")" ::: "memory");        \
    __builtin_amdgcn_s_barrier();                                \
    __builtin_amdgcn_sched_barrier(0);                           \
} while (0)

// global -> LDS direct DMA, 16B per lane
__device__ __forceinline__ void gload_lds16(const void* g, void* l) {
    __builtin_amdgcn_global_load_lds(
        (const __attribute__((address_space(1))) void*)g,
        (__attribute__((address_space(3))) void*)l, 16, 0, 0);
}

// ---------------------------------------------------------------------------
// Pre-convert: Wq/Wk/Wv -> bf16 (ws) and x -> bf16 (d_out scratch).
// ---------------------------------------------------------------------------
__global__ __launch_bounds__(256) void cvt_all(
    const float* __restrict__ W0, const float* __restrict__ W1, const float* __restrict__ W2,
    const float* __restrict__ X,
    unsigned short* __restrict__ Wb, unsigned short* __restrict__ Xb)
{
    const int y = blockIdx.y;
    const float* src;
    unsigned short* dst;
    if (y < 3) {
        src = (y == 0) ? W0 : (y == 1) ? W1 : W2;
        dst = Wb + (size_t)y * (DMODEL * DMODEL);
    } else {
        src = X + (size_t)(y - 3) * (DMODEL * DMODEL);
        dst = Xb + (size_t)(y - 3) * (DMODEL * DMODEL);
    }
    size_t idx = ((size_t)blockIdx.x * 256 + threadIdx.x) * 8;
    float4 a = *(const float4*)(src + idx);
    float4 b = *(const float4*)(src + idx + 4);
    u16x8 h;
    h[0] = f2bfu(a.x); h[1] = f2bfu(a.y); h[2] = f2bfu(a.z); h[3] = f2bfu(a.w);
    h[4] = f2bfu(b.x); h[5] = f2bfu(b.y); h[6] = f2bfu(b.z); h[7] = f2bfu(b.w);
    *(u16x8*)(dst + idx) = h;
}

// ---------------------------------------------------------------------------
// QKV MFMA GEMM (R16 pipeline) + R23 bijective XCD swizzle (T1):
// 768 blocks = 8 XCDs x 96; each XCD gets a contiguous chunk (4 full
// A-panel rows x 24 n-blocks) -> per-XCD A-refetch drops ~8x.
// ---------------------------------------------------------------------------
__global__ __launch_bounds__(256) void gemm_qkv(
    const unsigned short* __restrict__ Xb,
    const unsigned short* __restrict__ Wb,
    unsigned short* __restrict__ Yq, unsigned short* __restrict__ Yk, unsigned short* __restrict__ Yv)
{
    __shared__ __align__(16) unsigned char pool[49152];
    unsigned short* base = (unsigned short*)pool;

    const int tid  = threadIdx.x;
    const int wave = tid >> 6;
    const int lane = tid & 63;
    const int c    = lane & 15;
    const int quad = lane >> 4;

    // XCD swizzle: lin -> (xcd = lin&7) gets chunk [xcd*96, xcd*96+96)
    const int lin  = (int)(blockIdx.y * gridDim.x + blockIdx.x);   // 0..767
    const int nw   = (lin & 7) * 96 + (lin >> 3);
    const int m0 = (nw / 24) * 128;
    const int n0 = (nw % 24) * 128;
    const int w_idx = n0 >> 10;
    const int e0    = n0 & 1023;
    const unsigned short* Wsrc = Wb + (size_t)w_idx * (DMODEL * DMODEL);

    const int mhalf = (wave & 1) * 64;
    const int nhalf = (wave >> 1) * 64;

    f32x4 acc[4][4];
#pragma unroll
    for (int i = 0; i < 4; i++)
#pragma unroll
        for (int j = 0; j < 4; j++) acc[i][j] = (f32x4){0.f, 0.f, 0.f, 0.f};

    const int srow = wave * 32 + (lane >> 2);
    const int scol = (lane & 3) * 8;
    const unsigned short* Asrc = Xb   + (size_t)(m0 + srow) * DMODEL + scol;
    const unsigned short* Bsrc = Wsrc + (size_t)(e0 + srow) * DMODEL + scol;
    const int doff = srow * 32 + scol;

#define QKV_STAGE(buf, kt) do {                                                    \
    unsigned short* _A = base + (buf) * 8192;                                      \
    unsigned short* _B = _A + 4096;                                                \
    const int _k0 = (kt) * 32;                                                     \
    _Pragma("unroll")                                                              \
    for (int _j = 0; _j < 2; _j++) {                                               \
        gload_lds16(Asrc + (size_t)(_j * 16) * DMODEL + _k0, _A + doff + _j * 512);\
        gload_lds16(Bsrc + (size_t)(_j * 16) * DMODEL + _k0, _B + doff + _j * 512);\
    }                                                                              \
} while (0)

#define QKV_COMPUTE(buf) do {                                                      \
    const unsigned short* _A = base + (buf) * 8192;                                \
    const unsigned short* _B = _A + 4096;                                          \
    bf16x8 af[4], bfr[4];                                                          \
    _Pragma("unroll")                                                              \
    for (int mt = 0; mt < 4; mt++)                                                 \
        af[mt] = *(const bf16x8*)(&_A[(mhalf + mt * 16 + c) * 32 + quad * 8]);     \
    _Pragma("unroll")                                                              \
    for (int nt = 0; nt < 4; nt++)                                                 \
        bfr[nt] = *(const bf16x8*)(&_B[(nhalf + nt * 16 + c) * 32 + quad * 8]);    \
    _Pragma("unroll")                                                              \
    for (int mt = 0; mt < 4; mt++)                                                 \
        _Pragma("unroll")                                                          \
        for (int nt = 0; nt < 4; nt++)                                             \
            acc[mt][nt] = __builtin_amdgcn_mfma_f32_16x16x32_bf16(af[mt], bfr[nt], acc[mt][nt], 0, 0, 0); \
} while (0)

    QKV_STAGE(0, 0);
    QKV_STAGE(1, 1);
    for (int g = 0; g < 10; ++g) {
        const int t = g * 3;
        VMCNT_BAR(4); QKV_STAGE(2, t + 2); QKV_COMPUTE(0);
        VMCNT_BAR(4); QKV_STAGE(0, t + 3); QKV_COMPUTE(1);
        VMCNT_BAR(4); QKV_STAGE(1, t + 4); QKV_COMPUTE(2);
    }
    VMCNT_BAR(4); QKV_COMPUTE(0);
    VMCNT_BAR(0); QKV_COMPUTE(1);

    __syncthreads();

    const int h = (e0 + nhalf) >> 6;
    if (w_idx < 2) {
        unsigned short* Yqk = (w_idx == 0) ? Yq : Yk;
        float* EPf = (float*)pool + wave * 16 * 68;
        const int row = lane >> 2;
        const int cg  = lane & 3;
#pragma unroll
        for (int mt = 0; mt < 4; mt++) {
            LGKM0();
#pragma unroll
            for (int nt = 0; nt < 4; nt++)
#pragma unroll
                for (int r = 0; r < 4; r++)
                    EPf[(quad * 4 + r) * 68 + nt * 16 + c] = acc[mt][nt][r];
            LGKM0();
            float fl[16];
#pragma unroll
            for (int j = 0; j < 4; j++) {
                float4 v = *(const float4*)(&EPf[row * 68 + cg * 16 + j * 4]);
                fl[j * 4 + 0] = v.x; fl[j * 4 + 1] = v.y;
                fl[j * 4 + 2] = v.z; fl[j * 4 + 3] = v.w;
            }
            int m = m0 + mhalf + mt * 16 + row;
            int s = m & (S_LEN - 1);
            int b = m >> 11;
            u16x8 o0, o1;
#pragma unroll
            for (int pi = 0; pi < 8; pi++) {
                int p = cg * 8 + pi;
                float freq  = exp2f(-(float)p * 0.41524101186092034f);
                float angle = (float)s * freq;
                float sn, cs;
                __sincosf(angle, &sn, &cs);
                float ev = fl[2 * pi], ov = fl[2 * pi + 1];
                float re = ev * cs - ov * sn;
                float ro = ev * sn + ov * cs;
                if (pi < 4) { o0[2 * pi] = f2bfu(re); o0[2 * pi + 1] = f2bfu(ro); }
                else        { o1[2 * (pi - 4)] = f2bfu(re); o1[2 * (pi - 4) + 1] = f2bfu(ro); }
            }
            unsigned short* dst = Yqk + (((size_t)(b * NHEADS + h)) * S_LEN + s) * DKH + cg * 16;
            *(u16x8*)(dst)     = o0;
            *(u16x8*)(dst + 8) = o1;
        }
    } else {
        unsigned short* EPb = (unsigned short*)pool + wave * 64 * 72;
        LGKM0();
#pragma unroll
        for (int nt = 0; nt < 4; nt++)
#pragma unroll
            for (int mt = 0; mt < 4; mt++)
#pragma unroll
                for (int r = 0; r < 4; r++)
                    EPb[(nt * 16 + c) * 72 + mt * 16 + quad * 4 + r] = f2bfu(acc[mt][nt][r]);
        LGKM0();
        int mbase = m0 + mhalf;
        int s0 = mbase & (S_LEN - 1);
        int b  = mbase >> 11;
        unsigned short* dst = Yv + (((size_t)(b * NHEADS + h)) * DKH + lane) * S_LEN + s0;
#pragma unroll
        for (int j = 0; j < 8; j++)
            *(u16x8*)(dst + j * 8) = *(const u16x8*)(&EPb[lane * 72 + j * 8]);
    }
#undef QKV_STAGE
#undef QKV_COMPUTE
}

// ---------------------------------------------------------------------------
// Wo MFMA GEMM (R16 pipeline) + R23 XCD swizzle: 512 blocks = 8 x 64.
// ---------------------------------------------------------------------------
__global__ __launch_bounds__(256) void gemm_wo(
    const unsigned short* __restrict__ X,
    const unsigned short* __restrict__ Wob,
    float* __restrict__ Yf)
{
    __shared__ __align__(16) unsigned char pool[36864];
    unsigned short* base = (unsigned short*)pool;

    const int tid  = threadIdx.x;
    const int wave = tid >> 6;
    const int lane = tid & 63;
    const int c    = lane & 15;
    const int quad = lane >> 4;

    const int lin = (int)(blockIdx.y * gridDim.x + blockIdx.x);   // 0..511
    const int nw  = (lin & 7) * 64 + (lin >> 3);
    const int m0 = (nw / 8) * 64;
    const int n0 = (nw % 8) * 128;

    const int mhalf = (wave & 1) * 32;
    const int nhalf = (wave >> 1) * 64;

    f32x4 acc[2][4];
#pragma unroll
    for (int i = 0; i < 2; i++)
#pragma unroll
        for (int j = 0; j < 4; j++) acc[i][j] = (f32x4){0.f, 0.f, 0.f, 0.f};

    const int arow = wave * 16 + (lane >> 2);
    const int brow = wave * 32 + (lane >> 2);
    const int scol = (lane & 3) * 8;
    const unsigned short* Asrc = X   + (size_t)(m0 + arow) * DMODEL + scol;
    const unsigned short* Bsrc = Wob + (size_t)(n0 + brow) * DMODEL + scol;
    const int adoff = arow * 32 + scol;
    const int bdoff = brow * 32 + scol;

#define WO_STAGE(buf, kt) do {                                                     \
    unsigned short* _A = base + (buf) * 6144;                                      \
    unsigned short* _B = _A + 2048;                                                \
    const int _k0 = (kt) * 32;                                                     \
    gload_lds16(Asrc + _k0, _A + adoff);                                           \
    _Pragma("unroll")                                                              \
    for (int _j = 0; _j < 2; _j++)                                                 \
        gload_lds16(Bsrc + (size_t)(_j * 16) * DMODEL + _k0, _B + bdoff + _j * 512);\
} while (0)

#define WO_COMPUTE(buf) do {                                                       \
    const unsigned short* _A = base + (buf) * 6144;                                \
    const unsigned short* _B = _A + 2048;                                          \
    bf16x8 af[2], bfr[4];                                                          \
    _Pragma("unroll")                                                              \
    for (int mt = 0; mt < 2; mt++)                                                 \
        af[mt] = *(const bf16x8*)(&_A[(mhalf + mt * 16 + c) * 32 + quad * 8]);     \
    _Pragma("unroll")                                                              \
    for (int nt = 0; nt < 4; nt++)                                                 \
        bfr[nt] = *(const bf16x8*)(&_B[(nhalf + nt * 16 + c) * 32 + quad * 8]);    \
    _Pragma("unroll")                                                              \
    for (int mt = 0; mt < 2; mt++)                                                 \
        _Pragma("unroll")                                                          \
        for (int nt = 0; nt < 4; nt++)                                             \
            acc[mt][nt] = __builtin_amdgcn_mfma_f32_16x16x32_bf16(af[mt], bfr[nt], acc[mt][nt], 0, 0, 0); \
} while (0)

    WO_STAGE(0, 0);
    WO_STAGE(1, 1);
    for (int g = 0; g < 10; ++g) {
        const int t = g * 3;
        VMCNT_BAR(3); WO_STAGE(2, t + 2); WO_COMPUTE(0);
        VMCNT_BAR(3); WO_STAGE(0, t + 3); WO_COMPUTE(1);
        VMCNT_BAR(3); WO_STAGE(1, t + 4); WO_COMPUTE(2);
    }
    VMCNT_BAR(3); WO_COMPUTE(0);
    VMCNT_BAR(0); WO_COMPUTE(1);

    __syncthreads();

    float* EPf = (float*)pool + wave * 16 * 68;
    const int row = lane >> 2;
    const int cg  = lane & 3;
#pragma unroll
    for (int mt = 0; mt < 2; mt++) {
        LGKM0();
#pragma unroll
        for (int nt = 0; nt < 4; nt++)
#pragma unroll
            for (int r = 0; r < 4; r++)
                EPf[(quad * 4 + r) * 68 + nt * 16 + c] = acc[mt][nt][r];
        LGKM0();
        int m = m0 + mhalf + mt * 16 + row;
        float* dst = Yf + (size_t)m * DMODEL + n0 + nhalf + cg * 16;
#pragma unroll
        for (int j = 0; j < 4; j++)
            *(float4*)(dst + j * 4) = *(const float4*)(&EPf[row * 68 + cg * 16 + j * 4]);
    }
#undef WO_STAGE
#undef WO_COMPUTE
}

// ---------------------------------------------------------------------------
// MFMA flash attention R23 = EXACT R21 (measured-best ~40us): 32x32x16
// swapped-QK, split-KV, block-shared K/V dbuf + T14 split staging,
// permlane32_swap key exchange. R20/R22 lessons: occupancy-halving
// restructures and unprefetched direct-global K both regress.
// ---------------------------------------------------------------------------
__global__ __launch_bounds__(128, 4) void attn_mfma(
    const unsigned short* __restrict__ Q,
    const unsigned short* __restrict__ K,
    const unsigned short* __restrict__ Vt,
    unsigned short* __restrict__ A,
    float* __restrict__ Scr)
{
    __shared__ unsigned short Ks[2][32 * 72];   // [key][dk], stride 72
    __shared__ unsigned short Vs[2][64 * 40];   // [dv][key], stride 40

    const int tid  = threadIdx.x;
    const int wave = tid >> 6;    // 0..1
    const int lane = tid & 63;
    const int c32  = lane & 31;
    const int hi   = lane >> 5;

    const int bh = blockIdx.x;
    const int b  = bh >> 4;
    const int h  = bh & 15;

    // Piece mapping (identical to R18/R19/R21)
    const int R = (int)blockIdx.y;
    int qb, t_lo, t_hi, spl = 0;
    bool is_split;
    if (R <= 16) {
        qb = 16 - R; t_lo = 0; t_hi = 2 * qb + 2; is_split = false;
    } else {
        int i = R - 17;
        qb  = 31 - (i >> 1);
        spl = i & 1;
        int nk = 2 * qb + 2, half = nk >> 1;
        t_lo = spl ? half : 0;
        t_hi = spl ? nk   : half;
        is_split = true;
    }
    const int q0b = qb * 64;
    const int q0w = q0b + wave * 32;

    const unsigned short* Qb = Q  + (size_t)bh * S_LEN * DKH;
    const unsigned short* Kb = K  + (size_t)bh * S_LEN * DKH;
    const unsigned short* Vb = Vt + (size_t)bh * DKH * S_LEN;

    // Q B-frags: lane holds Q[q = q0w+c32][dk = t*16 + hi*8 + 0..7]
    bf16x8 qf0 = *(const bf16x8*)(Qb + (size_t)(q0w + c32) * DKH +  0 + hi * 8);
    bf16x8 qf1 = *(const bf16x8*)(Qb + (size_t)(q0w + c32) * DKH + 16 + hi * 8);
    bf16x8 qf2 = *(const bf16x8*)(Qb + (size_t)(q0w + c32) * DKH + 32 + hi * 8);
    bf16x8 qf3 = *(const bf16x8*)(Qb + (size_t)(q0w + c32) * DKH + 48 + hi * 8);

    f32x16 oA, oB;
#pragma unroll
    for (int r = 0; r < 16; r++) { oA[r] = 0.f; oB[r] = 0.f; }
    float lacc = 0.f;

    const int my_nkb = (q0w >> 5) + 1;   // tiles this wave computes
    const int kbf    = q0w >> 5;         // tiles < kbf are mask-free

    // staging (128 threads): K 32x64 halves, V 64x32 halves; 2 uint4 each
    const int krow = tid >> 2;           // 0..31
    const int kcol = (tid & 3) * 16;     // 0,16,32,48
    const int vrow = tid >> 1;           // 0..63
    const int vcol = (tid & 1) * 16;     // 0,16

    uint4 gK0 = *(const uint4*)(Kb + (size_t)(t_lo * 32 + krow) * DKH + kcol);
    uint4 gK1 = *(const uint4*)(Kb + (size_t)(t_lo * 32 + krow) * DKH + kcol + 8);
    uint4 gV0 = *(const uint4*)(Vb + (size_t)vrow * S_LEN + t_lo * 32 + vcol);
    uint4 gV1 = *(const uint4*)(Vb + (size_t)vrow * S_LEN + t_lo * 32 + vcol + 8);
    *(uint4*)(&Ks[t_lo & 1][krow * 72 + kcol])     = gK0;
    *(uint4*)(&Ks[t_lo & 1][krow * 72 + kcol + 8]) = gK1;
    *(uint4*)(&Vs[t_lo & 1][vrow * 40 + vcol])     = gV0;
    *(uint4*)(&Vs[t_lo & 1][vrow * 40 + vcol + 8]) = gV1;

    for (int kb = t_lo; kb < t_hi; kb++) {
        const int k0 = kb * 32;
        const int nb = kb + 1;
        const bool pre = nb < t_hi;
        __syncthreads();
        if (pre) {   // T14: issue loads now, LDS-write at end of iter
            gK0 = *(const uint4*)(Kb + (size_t)(nb * 32 + krow) * DKH + kcol);
            gK1 = *(const uint4*)(Kb + (size_t)(nb * 32 + krow) * DKH + kcol + 8);
            gV0 = *(const uint4*)(Vb + (size_t)vrow * S_LEN + nb * 32 + vcol);
            gV1 = *(const uint4*)(Vb + (size_t)vrow * S_LEN + nb * 32 + vcol + 8);
        }
        if (kb < my_nkb) {
            const unsigned short* Kc = &Ks[kb & 1][0];
            const unsigned short* Vc = &Vs[kb & 1][0];
            bf16x8 kf0 = *(const bf16x8*)(&Kc[c32 * 72 +  0 + hi * 8]);
            bf16x8 kf1 = *(const bf16x8*)(&Kc[c32 * 72 + 16 + hi * 8]);
            bf16x8 kf2 = *(const bf16x8*)(&Kc[c32 * 72 + 32 + hi * 8]);
            bf16x8 kf3 = *(const bf16x8*)(&Kc[c32 * 72 + 48 + hi * 8]);
            f32x16 s;
#pragma unroll
            for (int r = 0; r < 16; r++) s[r] = 0.f;
            __builtin_amdgcn_s_setprio(1);
            s = __builtin_amdgcn_mfma_f32_32x32x16_bf16(kf0, qf0, s, 0, 0, 0);
            s = __builtin_amdgcn_mfma_f32_32x32x16_bf16(kf1, qf1, s, 0, 0, 0);
            s = __builtin_amdgcn_mfma_f32_32x32x16_bf16(kf2, qf2, s, 0, 0, 0);
            s = __builtin_amdgcn_mfma_f32_32x32x16_bf16(kf3, qf3, s, 0, 0, 0);
            __builtin_amdgcn_s_setprio(0);
            // s[r] = S[key = k0 + (r&3)+8*(r>>2)+4*hi][q = q0w + c32]
            float p[16];
            if (kb < kbf) {
#pragma unroll
                for (int r = 0; r < 16; r++) p[r] = __expf(s[r] * 0.125f);
            } else {
                const int qg = q0w + c32;
#pragma unroll
                for (int r = 0; r < 16; r++) {
                    int kg = k0 + (r & 3) + 8 * (r >> 2) + 4 * hi;
                    p[r] = (kg <= qg) ? __expf(s[r] * 0.125f) : 0.0f;
                }
            }
            // pack to bf16 pairs; accumulate l from ROUNDED values
            unsigned pk[8];
#pragma unroll
            for (int i = 0; i < 8; i++) {
                asm("v_cvt_pk_bf16_f32 %0, %1, %2"
                    : "=v"(pk[i]) : "v"(p[2 * i]), "v"(p[2 * i + 1]));
                union { unsigned u; float f; } lo, hx;
                lo.u = pk[i] << 16;
                hx.u = pk[i] & 0xffff0000u;
                lacc += lo.f + hx.f;
            }
            // key-half exchange via permlane32_swap (verified R21)
            u32x2 s02 = __builtin_amdgcn_permlane32_swap(pk[0], pk[2], false, false);
            u32x2 s13 = __builtin_amdgcn_permlane32_swap(pk[1], pk[3], false, false);
            u32x2 s46 = __builtin_amdgcn_permlane32_swap(pk[4], pk[6], false, false);
            u32x2 s57 = __builtin_amdgcn_permlane32_swap(pk[5], pk[7], false, false);
            union { unsigned u[4]; bf16x8 v; } pa0, pa1;
            pa0.u[0] = s02[0]; pa0.u[1] = s13[0]; pa0.u[2] = s02[1]; pa0.u[3] = s13[1];
            pa1.u[0] = s46[0]; pa1.u[1] = s57[0]; pa1.u[2] = s46[1]; pa1.u[3] = s57[1];
            bf16x8 v00 = *(const bf16x8*)(&Vc[(c32)      * 40 +  0 + hi * 8]);
            bf16x8 v10 = *(const bf16x8*)(&Vc[(c32)      * 40 + 16 + hi * 8]);
            bf16x8 v01 = *(const bf16x8*)(&Vc[(32 + c32) * 40 +  0 + hi * 8]);
            bf16x8 v11 = *(const bf16x8*)(&Vc[(32 + c32) * 40 + 16 + hi * 8]);
            __builtin_amdgcn_s_setprio(1);
            oA = __builtin_amdgcn_mfma_f32_32x32x16_bf16(pa0.v, v00, oA, 0, 0, 0);
            oA = __builtin_amdgcn_mfma_f32_32x32x16_bf16(pa1.v, v10, oA, 0, 0, 0);
            oB = __builtin_amdgcn_mfma_f32_32x32x16_bf16(pa0.v, v01, oB, 0, 0, 0);
            oB = __builtin_amdgcn_mfma_f32_32x32x16_bf16(pa1.v, v11, oB, 0, 0, 0);
            __builtin_amdgcn_s_setprio(0);
        }
        if (pre) {   // LDS write after compute (vmcnt paid post-overlap)
            *(uint4*)(&Ks[nb & 1][krow * 72 + kcol])     = gK0;
            *(uint4*)(&Ks[nb & 1][krow * 72 + kcol + 8]) = gK1;
            *(uint4*)(&Vs[nb & 1][vrow * 40 + vcol])     = gV0;
            *(uint4*)(&Vs[nb & 1][vrow * 40 + vcol + 8]) = gV1;
        }
    }

    // combine halves: full l for q = q0w + c32 at every lane
    lacc += __shfl_xor(lacc, 32, 64);

    if (!is_split) {
        float inv = 1.0f / lacc;
#pragma unroll
        for (int r = 0; r < 16; r++) {
            int qr = (r & 3) + 8 * (r >> 2) + 4 * hi;   // output q-row of reg r
            float invr = __shfl(inv, qr, 64);
            int sg = q0w + qr;
            unsigned short* Ap = A + ((size_t)b * S_LEN + sg) * DMODEL + h * DKH;
            Ap[c32]      = f2bfu(oA[r] * invr);
            Ap[32 + c32] = f2bfu(oB[r] * invr);
        }
    } else {
        const int slot = bh * SLOTS_BH + (qb - SPLIT_Q0) * 2 + spl;
        float* Po = Scr + (size_t)slot * 4096;
        float* Pl = Scr + PO_FLOATS + (size_t)slot * 64;
#pragma unroll
        for (int r = 0; r < 16; r++) {
            int qr  = (r & 3) + 8 * (r >> 2) + 4 * hi;
            int row = wave * 32 + qr;
            Po[row * 64 + c32]      = oA[r];
            Po[row * 64 + 32 + c32] = oB[r];
        }
        if (hi == 0) Pl[wave * 32 + c32] = lacc;
    }
}

// ---------------------------------------------------------------------------
// Merged combine + Wo-convert: blocks [0,480) combine split partials;
// blocks [480,992) convert Wo -> bf16.
// ---------------------------------------------------------------------------
__global__ __launch_bounds__(256) void combine_cvtwo(
    const float* __restrict__ Scr, unsigned short* __restrict__ A,
    const float* __restrict__ Wo, unsigned short* __restrict__ Wob)
{
    if (blockIdx.x >= 480) {
        size_t idx = ((size_t)(blockIdx.x - 480) * 256 + threadIdx.x) * 8;
        float4 a = *(const float4*)(Wo + idx);
        float4 b = *(const float4*)(Wo + idx + 4);
        u16x8 hh;
        hh[0] = f2bfu(a.x); hh[1] = f2bfu(a.y); hh[2] = f2bfu(a.z); hh[3] = f2bfu(a.w);
        hh[4] = f2bfu(b.x); hh[5] = f2bfu(b.y); hh[6] = f2bfu(b.z); hh[7] = f2bfu(b.w);
        *(u16x8*)(Wob + idx) = hh;
        return;
    }
    const int bx  = blockIdx.x;
    const int bh  = bx / 15;
    const int qbm = bx % 15;
    const int qb  = SPLIT_Q0 + qbm;
    const int b   = bh >> 4;
    const int h   = bh & 15;

    const int slot0 = bh * SLOTS_BH + qbm * 2;
    const float* O0 = Scr + (size_t)slot0 * 4096;
    const float* O1 = O0 + 4096;
    const float* L0 = Scr + PO_FLOATS + (size_t)slot0 * 64;
    const float* L1 = L0 + 64;

    const int r  = threadIdx.x >> 2;
    const int cg = (threadIdx.x & 3) * 16;

    float inv = 1.0f / (L0[r] + L1[r]);

    u16x8 outv[2];
#pragma unroll
    for (int half = 0; half < 2; half++) {
        float4 a0 = *(const float4*)(O0 + r * 64 + cg + half * 8);
        float4 b0 = *(const float4*)(O0 + r * 64 + cg + half * 8 + 4);
        float4 a1 = *(const float4*)(O1 + r * 64 + cg + half * 8);
        float4 b1 = *(const float4*)(O1 + r * 64 + cg + half * 8 + 4);
        outv[half][0] = f2bfu((a0.x + a1.x) * inv);
        outv[half][1] = f2bfu((a0.y + a1.y) * inv);
        outv[half][2] = f2bfu((a0.z + a1.z) * inv);
        outv[half][3] = f2bfu((a0.w + a1.w) * inv);
        outv[half][4] = f2bfu((b0.x + b1.x) * inv);
        outv[half][5] = f2bfu((b0.y + b1.y) * inv);
        outv[half][6] = f2bfu((b0.z + b1.z) * inv);
        outv[half][7] = f2bfu((b0.w + b1.w) * inv);
    }
    const int s = qb * 64 + r;
    unsigned short* Ap = A + ((size_t)b * S_LEN + s) * DMODEL + h * DKH + cg;
    *(u16x8*)(Ap)     = outv[0];
    *(u16x8*)(Ap + 8) = outv[1];
}

extern "C" void kernel_launch(void* const* d_in, const int* in_sizes, int n_in,
                              void* d_out, int out_size, void* d_ws, size_t ws_size,
                              hipStream_t stream) {
    const float* x  = (const float*)d_in[0];
    const float* Wq = (const float*)d_in[1];
    const float* Wk = (const float*)d_in[2];
    const float* Wv = (const float*)d_in[3];
    const float* Wo = (const float*)d_in[4];
    float* out = (float*)d_out;

    unsigned short* Qw = (unsigned short*)d_ws;
    unsigned short* Kw = Qw + (size_t)MROWS * DMODEL;
    unsigned short* Vw = Kw + (size_t)MROWS * DMODEL;
    unsigned short* Wb = Vw + (size_t)MROWS * DMODEL;
    unsigned short* Aw = Wb;    // aliased; QKV completes before attn writes A
    unsigned short* Wob = Qw;   // aliased; Q dead after attn_mfma
    unsigned short* Xb = (unsigned short*)d_out;
    float* Scr = (float*)d_out;

    cvt_all<<<dim3(DMODEL * DMODEL / (256 * 8), 7), 256, 0, stream>>>(Wq, Wk, Wv, x, Wb, Xb);

    gemm_qkv<<<dim3(3 * DMODEL / 128, MROWS / 128), 256, 0, stream>>>(
        Xb, Wb, Qw, Kw, Vw);

    attn_mfma<<<dim3(NHEADS * BATCH, NPIECE), 128, 0, stream>>>(Qw, Kw, Vw, Aw, Scr);

    combine_cvtwo<<<dim3(480 + 512), 256, 0, stream>>>(Scr, Aw, Wo, Wob);

    gemm_wo<<<dim3(DMODEL / 128, MROWS / 64), 256, 0, stream>>>(Aw, Wob, out);
}

// Round 12
// 177.404 us; speedup vs baseline: 1.2113x; 1.0251x over previous
//
#include <hip/hip_runtime.h>
#include <hip/hip_bf16.h>
#include <math.h>

// Problem constants
#define S_LEN   2048
#define BATCH   2
#define DMODEL  1024
#define NHEADS  16
#define DKH     64
#define MROWS   (BATCH * S_LEN)   // 4096

// attn split-KV geometry (R19/R21, measured-best): QBLK=64, KVBLK=32.
#define SPLIT_Q0   17
#define NPIECE     47
#define SLOTS_BH   30
#define PO_FLOATS  (960 * 4096)

typedef __attribute__((ext_vector_type(8)))  __bf16 bf16x8;
typedef __attribute__((ext_vector_type(4)))  float  f32x4;
typedef __attribute__((ext_vector_type(16))) float  f32x16;
typedef __attribute__((ext_vector_type(8)))  unsigned short u16x8;
typedef __attribute__((ext_vector_type(2)))  unsigned int   u32x2;

__device__ __forceinline__ float bfu2f(unsigned short u) {
    union { unsigned int i; float f; } v;
    v.i = ((unsigned int)u) << 16;
    return v.f;
}

__device__ __forceinline__ unsigned short f2bfu(float f) {
    union { __bf16 h; unsigned short u; } v;
    v.h = (__bf16)f;    // native RNE cvt
    return v.u;
}

#define LGKM0() __builtin_amdgcn_s_waitcnt(0xc07f)   // lgkmcnt(0), vmcnt free

// counted-vmcnt + raw barrier (T4)
#define VMCNT_BAR(n) do {                                        \
    asm volatile("s_waitcnt vmcnt(" #n ")" ::: "memory");        \
    __builtin_amdgcn_s_barrier();                                \
    __builtin_amdgcn_sched_barrier(0);                           \
} while (0)

// global -> LDS direct DMA, 16B per lane
__device__ __forceinline__ void gload_lds16(const void* g, void* l) {
    __builtin_amdgcn_global_load_lds(
        (const __attribute__((address_space(1))) void*)g,
        (__attribute__((address_space(3))) void*)l, 16, 0, 0);
}

// ---------------------------------------------------------------------------
// Pre-convert: Wq/Wk/Wv -> bf16 (ws) and x -> bf16 (d_out scratch).
// ---------------------------------------------------------------------------
__global__ __launch_bounds__(256) void cvt_all(
    const float* __restrict__ W0, const float* __restrict__ W1, const float* __restrict__ W2,
    const float* __restrict__ X,
    unsigned short* __restrict__ Wb, unsigned short* __restrict__ Xb)
{
    const int y = blockIdx.y;
    const float* src;
    unsigned short* dst;
    if (y < 3) {
        src = (y == 0) ? W0 : (y == 1) ? W1 : W2;
        dst = Wb + (size_t)y * (DMODEL * DMODEL);
    } else {
        src = X + (size_t)(y - 3) * (DMODEL * DMODEL);
        dst = Xb + (size_t)(y - 3) * (DMODEL * DMODEL);
    }
    size_t idx = ((size_t)blockIdx.x * 256 + threadIdx.x) * 8;
    float4 a = *(const float4*)(src + idx);
    float4 b = *(const float4*)(src + idx + 4);
    u16x8 h;
    h[0] = f2bfu(a.x); h[1] = f2bfu(a.y); h[2] = f2bfu(a.z); h[3] = f2bfu(a.w);
    h[4] = f2bfu(b.x); h[5] = f2bfu(b.y); h[6] = f2bfu(b.z); h[7] = f2bfu(b.w);
    *(u16x8*)(dst + idx) = h;
}

// ---------------------------------------------------------------------------
// QKV MFMA GEMM (R16, measured-best): 3-buffer counted-vmcnt pipeline.
// ---------------------------------------------------------------------------
__global__ __launch_bounds__(256) void gemm_qkv(
    const unsigned short* __restrict__ Xb,
    const unsigned short* __restrict__ Wb,
    unsigned short* __restrict__ Yq, unsigned short* __restrict__ Yk, unsigned short* __restrict__ Yv)
{
    __shared__ __align__(16) unsigned char pool[49152];
    unsigned short* base = (unsigned short*)pool;

    const int tid  = threadIdx.x;
    const int wave = tid >> 6;
    const int lane = tid & 63;
    const int c    = lane & 15;
    const int quad = lane >> 4;

    const int m0 = blockIdx.y * 128;
    const int n0 = blockIdx.x * 128;
    const int w_idx = n0 >> 10;
    const int e0    = n0 & 1023;
    const unsigned short* Wsrc = Wb + (size_t)w_idx * (DMODEL * DMODEL);

    const int mhalf = (wave & 1) * 64;
    const int nhalf = (wave >> 1) * 64;

    f32x4 acc[4][4];
#pragma unroll
    for (int i = 0; i < 4; i++)
#pragma unroll
        for (int j = 0; j < 4; j++) acc[i][j] = (f32x4){0.f, 0.f, 0.f, 0.f};

    const int srow = wave * 32 + (lane >> 2);
    const int scol = (lane & 3) * 8;
    const unsigned short* Asrc = Xb   + (size_t)(m0 + srow) * DMODEL + scol;
    const unsigned short* Bsrc = Wsrc + (size_t)(e0 + srow) * DMODEL + scol;
    const int doff = srow * 32 + scol;

#define QKV_STAGE(buf, kt) do {                                                    \
    unsigned short* _A = base + (buf) * 8192;                                      \
    unsigned short* _B = _A + 4096;                                                \
    const int _k0 = (kt) * 32;                                                     \
    _Pragma("unroll")                                                              \
    for (int _j = 0; _j < 2; _j++) {                                               \
        gload_lds16(Asrc + (size_t)(_j * 16) * DMODEL + _k0, _A + doff + _j * 512);\
        gload_lds16(Bsrc + (size_t)(_j * 16) * DMODEL + _k0, _B + doff + _j * 512);\
    }                                                                              \
} while (0)

#define QKV_COMPUTE(buf) do {                                                      \
    const unsigned short* _A = base + (buf) * 8192;                                \
    const unsigned short* _B = _A + 4096;                                          \
    bf16x8 af[4], bfr[4];                                                          \
    _Pragma("unroll")                                                              \
    for (int mt = 0; mt < 4; mt++)                                                 \
        af[mt] = *(const bf16x8*)(&_A[(mhalf + mt * 16 + c) * 32 + quad * 8]);     \
    _Pragma("unroll")                                                              \
    for (int nt = 0; nt < 4; nt++)                                                 \
        bfr[nt] = *(const bf16x8*)(&_B[(nhalf + nt * 16 + c) * 32 + quad * 8]);    \
    _Pragma("unroll")                                                              \
    for (int mt = 0; mt < 4; mt++)                                                 \
        _Pragma("unroll")                                                          \
        for (int nt = 0; nt < 4; nt++)                                             \
            acc[mt][nt] = __builtin_amdgcn_mfma_f32_16x16x32_bf16(af[mt], bfr[nt], acc[mt][nt], 0, 0, 0); \
} while (0)

    QKV_STAGE(0, 0);
    QKV_STAGE(1, 1);
    for (int g = 0; g < 10; ++g) {
        const int t = g * 3;
        VMCNT_BAR(4); QKV_STAGE(2, t + 2); QKV_COMPUTE(0);
        VMCNT_BAR(4); QKV_STAGE(0, t + 3); QKV_COMPUTE(1);
        VMCNT_BAR(4); QKV_STAGE(1, t + 4); QKV_COMPUTE(2);
    }
    VMCNT_BAR(4); QKV_COMPUTE(0);
    VMCNT_BAR(0); QKV_COMPUTE(1);

    __syncthreads();

    const int h = (e0 + nhalf) >> 6;
    if (w_idx < 2) {
        unsigned short* Yqk = (w_idx == 0) ? Yq : Yk;
        float* EPf = (float*)pool + wave * 16 * 68;
        const int row = lane >> 2;
        const int cg  = lane & 3;
#pragma unroll
        for (int mt = 0; mt < 4; mt++) {
            LGKM0();
#pragma unroll
            for (int nt = 0; nt < 4; nt++)
#pragma unroll
                for (int r = 0; r < 4; r++)
                    EPf[(quad * 4 + r) * 68 + nt * 16 + c] = acc[mt][nt][r];
            LGKM0();
            float fl[16];
#pragma unroll
            for (int j = 0; j < 4; j++) {
                float4 v = *(const float4*)(&EPf[row * 68 + cg * 16 + j * 4]);
                fl[j * 4 + 0] = v.x; fl[j * 4 + 1] = v.y;
                fl[j * 4 + 2] = v.z; fl[j * 4 + 3] = v.w;
            }
            int m = m0 + mhalf + mt * 16 + row;
            int s = m & (S_LEN - 1);
            int b = m >> 11;
            u16x8 o0, o1;
#pragma unroll
            for (int pi = 0; pi < 8; pi++) {
                int p = cg * 8 + pi;
                float freq  = exp2f(-(float)p * 0.41524101186092034f);
                float angle = (float)s * freq;
                float sn, cs;
                __sincosf(angle, &sn, &cs);
                float ev = fl[2 * pi], ov = fl[2 * pi + 1];
                float re = ev * cs - ov * sn;
                float ro = ev * sn + ov * cs;
                if (pi < 4) { o0[2 * pi] = f2bfu(re); o0[2 * pi + 1] = f2bfu(ro); }
                else        { o1[2 * (pi - 4)] = f2bfu(re); o1[2 * (pi - 4) + 1] = f2bfu(ro); }
            }
            unsigned short* dst = Yqk + (((size_t)(b * NHEADS + h)) * S_LEN + s) * DKH + cg * 16;
            *(u16x8*)(dst)     = o0;
            *(u16x8*)(dst + 8) = o1;
        }
    } else {
        unsigned short* EPb = (unsigned short*)pool + wave * 64 * 72;
        LGKM0();
#pragma unroll
        for (int nt = 0; nt < 4; nt++)
#pragma unroll
            for (int mt = 0; mt < 4; mt++)
#pragma unroll
                for (int r = 0; r < 4; r++)
                    EPb[(nt * 16 + c) * 72 + mt * 16 + quad * 4 + r] = f2bfu(acc[mt][nt][r]);
        LGKM0();
        int mbase = m0 + mhalf;
        int s0 = mbase & (S_LEN - 1);
        int b  = mbase >> 11;
        unsigned short* dst = Yv + (((size_t)(b * NHEADS + h)) * DKH + lane) * S_LEN + s0;
#pragma unroll
        for (int j = 0; j < 8; j++)
            *(u16x8*)(dst + j * 8) = *(const u16x8*)(&EPb[lane * 72 + j * 8]);
    }
#undef QKV_STAGE
#undef QKV_COMPUTE
}

// ---------------------------------------------------------------------------
// Wo MFMA GEMM (R16, measured-best): 3-buffer counted-vmcnt, 64x128, BK=32.
// ---------------------------------------------------------------------------
__global__ __launch_bounds__(256) void gemm_wo(
    const unsigned short* __restrict__ X,
    const unsigned short* __restrict__ Wob,
    float* __restrict__ Yf)
{
    __shared__ __align__(16) unsigned char pool[36864];
    unsigned short* base = (unsigned short*)pool;

    const int tid  = threadIdx.x;
    const int wave = tid >> 6;
    const int lane = tid & 63;
    const int c    = lane & 15;
    const int quad = lane >> 4;

    const int m0 = blockIdx.y * 64;
    const int n0 = blockIdx.x * 128;

    const int mhalf = (wave & 1) * 32;
    const int nhalf = (wave >> 1) * 64;

    f32x4 acc[2][4];
#pragma unroll
    for (int i = 0; i < 2; i++)
#pragma unroll
        for (int j = 0; j < 4; j++) acc[i][j] = (f32x4){0.f, 0.f, 0.f, 0.f};

    const int arow = wave * 16 + (lane >> 2);
    const int brow = wave * 32 + (lane >> 2);
    const int scol = (lane & 3) * 8;
    const unsigned short* Asrc = X   + (size_t)(m0 + arow) * DMODEL + scol;
    const unsigned short* Bsrc = Wob + (size_t)(n0 + brow) * DMODEL + scol;
    const int adoff = arow * 32 + scol;
    const int bdoff = brow * 32 + scol;

#define WO_STAGE(buf, kt) do {                                                     \
    unsigned short* _A = base + (buf) * 6144;                                      \
    unsigned short* _B = _A + 2048;                                                \
    const int _k0 = (kt) * 32;                                                     \
    gload_lds16(Asrc + _k0, _A + adoff);                                           \
    _Pragma("unroll")                                                              \
    for (int _j = 0; _j < 2; _j++)                                                 \
        gload_lds16(Bsrc + (size_t)(_j * 16) * DMODEL + _k0, _B + bdoff + _j * 512);\
} while (0)

#define WO_COMPUTE(buf) do {                                                       \
    const unsigned short* _A = base + (buf) * 6144;                                \
    const unsigned short* _B = _A + 2048;                                          \
    bf16x8 af[2], bfr[4];                                                          \
    _Pragma("unroll")                                                              \
    for (int mt = 0; mt < 2; mt++)                                                 \
        af[mt] = *(const bf16x8*)(&_A[(mhalf + mt * 16 + c) * 32 + quad * 8]);     \
    _Pragma("unroll")                                                              \
    for (int nt = 0; nt < 4; nt++)                                                 \
        bfr[nt] = *(const bf16x8*)(&_B[(nhalf + nt * 16 + c) * 32 + quad * 8]);    \
    _Pragma("unroll")                                                              \
    for (int mt = 0; mt < 2; mt++)                                                 \
        _Pragma("unroll")                                                          \
        for (int nt = 0; nt < 4; nt++)                                             \
            acc[mt][nt] = __builtin_amdgcn_mfma_f32_16x16x32_bf16(af[mt], bfr[nt], acc[mt][nt], 0, 0, 0); \
} while (0)

    WO_STAGE(0, 0);
    WO_STAGE(1, 1);
    for (int g = 0; g < 10; ++g) {
        const int t = g * 3;
        VMCNT_BAR(3); WO_STAGE(2, t + 2); WO_COMPUTE(0);
        VMCNT_BAR(3); WO_STAGE(0, t + 3); WO_COMPUTE(1);
        VMCNT_BAR(3); WO_STAGE(1, t + 4); WO_COMPUTE(2);
    }
    VMCNT_BAR(3); WO_COMPUTE(0);
    VMCNT_BAR(0); WO_COMPUTE(1);

    __syncthreads();

    float* EPf = (float*)pool + wave * 16 * 68;
    const int row = lane >> 2;
    const int cg  = lane & 3;
#pragma unroll
    for (int mt = 0; mt < 2; mt++) {
        LGKM0();
#pragma unroll
        for (int nt = 0; nt < 4; nt++)
#pragma unroll
            for (int r = 0; r < 4; r++)
                EPf[(quad * 4 + r) * 68 + nt * 16 + c] = acc[mt][nt][r];
        LGKM0();
        int m = m0 + mhalf + mt * 16 + row;
        float* dst = Yf + (size_t)m * DMODEL + n0 + nhalf + cg * 16;
#pragma unroll
        for (int j = 0; j < 4; j++)
            *(float4*)(dst + j * 4) = *(const float4*)(&EPf[row * 68 + cg * 16 + j * 4]);
    }
#undef WO_STAGE
#undef WO_COMPUTE
}

// ---------------------------------------------------------------------------
// MFMA flash attention (R21, measured-best ~40us): 32x32x16 swapped-QK,
// split-KV, block-shared K/V dbuf + T14 split staging, permlane32_swap
// key exchange. R20/R22/R23 lessons: occupancy-halving restructures,
// unprefetched direct-global K, and GEMM XCD swizzle all regress.
// ---------------------------------------------------------------------------
__global__ __launch_bounds__(128, 4) void attn_mfma(
    const unsigned short* __restrict__ Q,
    const unsigned short* __restrict__ K,
    const unsigned short* __restrict__ Vt,
    unsigned short* __restrict__ A,
    float* __restrict__ Scr)
{
    __shared__ unsigned short Ks[2][32 * 72];   // [key][dk], stride 72
    __shared__ unsigned short Vs[2][64 * 40];   // [dv][key], stride 40

    const int tid  = threadIdx.x;
    const int wave = tid >> 6;    // 0..1
    const int lane = tid & 63;
    const int c32  = lane & 31;
    const int hi   = lane >> 5;

    const int bh = blockIdx.x;
    const int b  = bh >> 4;
    const int h  = bh & 15;

    // Piece mapping (identical to R18/R19/R21)
    const int R = (int)blockIdx.y;
    int qb, t_lo, t_hi, spl = 0;
    bool is_split;
    if (R <= 16) {
        qb = 16 - R; t_lo = 0; t_hi = 2 * qb + 2; is_split = false;
    } else {
        int i = R - 17;
        qb  = 31 - (i >> 1);
        spl = i & 1;
        int nk = 2 * qb + 2, half = nk >> 1;
        t_lo = spl ? half : 0;
        t_hi = spl ? nk   : half;
        is_split = true;
    }
    const int q0b = qb * 64;
    const int q0w = q0b + wave * 32;

    const unsigned short* Qb = Q  + (size_t)bh * S_LEN * DKH;
    const unsigned short* Kb = K  + (size_t)bh * S_LEN * DKH;
    const unsigned short* Vb = Vt + (size_t)bh * DKH * S_LEN;

    // Q B-frags: lane holds Q[q = q0w+c32][dk = t*16 + hi*8 + 0..7]
    bf16x8 qf0 = *(const bf16x8*)(Qb + (size_t)(q0w + c32) * DKH +  0 + hi * 8);
    bf16x8 qf1 = *(const bf16x8*)(Qb + (size_t)(q0w + c32) * DKH + 16 + hi * 8);
    bf16x8 qf2 = *(const bf16x8*)(Qb + (size_t)(q0w + c32) * DKH + 32 + hi * 8);
    bf16x8 qf3 = *(const bf16x8*)(Qb + (size_t)(q0w + c32) * DKH + 48 + hi * 8);

    f32x16 oA, oB;
#pragma unroll
    for (int r = 0; r < 16; r++) { oA[r] = 0.f; oB[r] = 0.f; }
    float lacc = 0.f;

    const int my_nkb = (q0w >> 5) + 1;   // tiles this wave computes
    const int kbf    = q0w >> 5;         // tiles < kbf are mask-free

    // staging (128 threads): K 32x64 halves, V 64x32 halves; 2 uint4 each
    const int krow = tid >> 2;           // 0..31
    const int kcol = (tid & 3) * 16;     // 0,16,32,48
    const int vrow = tid >> 1;           // 0..63
    const int vcol = (tid & 1) * 16;     // 0,16

    uint4 gK0 = *(const uint4*)(Kb + (size_t)(t_lo * 32 + krow) * DKH + kcol);
    uint4 gK1 = *(const uint4*)(Kb + (size_t)(t_lo * 32 + krow) * DKH + kcol + 8);
    uint4 gV0 = *(const uint4*)(Vb + (size_t)vrow * S_LEN + t_lo * 32 + vcol);
    uint4 gV1 = *(const uint4*)(Vb + (size_t)vrow * S_LEN + t_lo * 32 + vcol + 8);
    *(uint4*)(&Ks[t_lo & 1][krow * 72 + kcol])     = gK0;
    *(uint4*)(&Ks[t_lo & 1][krow * 72 + kcol + 8]) = gK1;
    *(uint4*)(&Vs[t_lo & 1][vrow * 40 + vcol])     = gV0;
    *(uint4*)(&Vs[t_lo & 1][vrow * 40 + vcol + 8]) = gV1;

    for (int kb = t_lo; kb < t_hi; kb++) {
        const int k0 = kb * 32;
        const int nb = kb + 1;
        const bool pre = nb < t_hi;
        __syncthreads();
        if (pre) {   // T14: issue loads now, LDS-write at end of iter
            gK0 = *(const uint4*)(Kb + (size_t)(nb * 32 + krow) * DKH + kcol);
            gK1 = *(const uint4*)(Kb + (size_t)(nb * 32 + krow) * DKH + kcol + 8);
            gV0 = *(const uint4*)(Vb + (size_t)vrow * S_LEN + nb * 32 + vcol);
            gV1 = *(const uint4*)(Vb + (size_t)vrow * S_LEN + nb * 32 + vcol + 8);
        }
        if (kb < my_nkb) {
            const unsigned short* Kc = &Ks[kb & 1][0];
            const unsigned short* Vc = &Vs[kb & 1][0];
            bf16x8 kf0 = *(const bf16x8*)(&Kc[c32 * 72 +  0 + hi * 8]);
            bf16x8 kf1 = *(const bf16x8*)(&Kc[c32 * 72 + 16 + hi * 8]);
            bf16x8 kf2 = *(const bf16x8*)(&Kc[c32 * 72 + 32 + hi * 8]);
            bf16x8 kf3 = *(const bf16x8*)(&Kc[c32 * 72 + 48 + hi * 8]);
            f32x16 s;
#pragma unroll
            for (int r = 0; r < 16; r++) s[r] = 0.f;
            __builtin_amdgcn_s_setprio(1);
            s = __builtin_amdgcn_mfma_f32_32x32x16_bf16(kf0, qf0, s, 0, 0, 0);
            s = __builtin_amdgcn_mfma_f32_32x32x16_bf16(kf1, qf1, s, 0, 0, 0);
            s = __builtin_amdgcn_mfma_f32_32x32x16_bf16(kf2, qf2, s, 0, 0, 0);
            s = __builtin_amdgcn_mfma_f32_32x32x16_bf16(kf3, qf3, s, 0, 0, 0);
            __builtin_amdgcn_s_setprio(0);
            // s[r] = S[key = k0 + (r&3)+8*(r>>2)+4*hi][q = q0w + c32]
            float p[16];
            if (kb < kbf) {
#pragma unroll
                for (int r = 0; r < 16; r++) p[r] = __expf(s[r] * 0.125f);
            } else {
                const int qg = q0w + c32;
#pragma unroll
                for (int r = 0; r < 16; r++) {
                    int kg = k0 + (r & 3) + 8 * (r >> 2) + 4 * hi;
                    p[r] = (kg <= qg) ? __expf(s[r] * 0.125f) : 0.0f;
                }
            }
            // pack to bf16 pairs; accumulate l from ROUNDED values
            unsigned pk[8];
#pragma unroll
            for (int i = 0; i < 8; i++) {
                asm("v_cvt_pk_bf16_f32 %0, %1, %2"
                    : "=v"(pk[i]) : "v"(p[2 * i]), "v"(p[2 * i + 1]));
                union { unsigned u; float f; } lo, hx;
                lo.u = pk[i] << 16;
                hx.u = pk[i] & 0xffff0000u;
                lacc += lo.f + hx.f;
            }
            // key-half exchange via permlane32_swap (verified R21)
            u32x2 s02 = __builtin_amdgcn_permlane32_swap(pk[0], pk[2], false, false);
            u32x2 s13 = __builtin_amdgcn_permlane32_swap(pk[1], pk[3], false, false);
            u32x2 s46 = __builtin_amdgcn_permlane32_swap(pk[4], pk[6], false, false);
            u32x2 s57 = __builtin_amdgcn_permlane32_swap(pk[5], pk[7], false, false);
            union { unsigned u[4]; bf16x8 v; } pa0, pa1;
            pa0.u[0] = s02[0]; pa0.u[1] = s13[0]; pa0.u[2] = s02[1]; pa0.u[3] = s13[1];
            pa1.u[0] = s46[0]; pa1.u[1] = s57[0]; pa1.u[2] = s46[1]; pa1.u[3] = s57[1];
            bf16x8 v00 = *(const bf16x8*)(&Vc[(c32)      * 40 +  0 + hi * 8]);
            bf16x8 v10 = *(const bf16x8*)(&Vc[(c32)      * 40 + 16 + hi * 8]);
            bf16x8 v01 = *(const bf16x8*)(&Vc[(32 + c32) * 40 +  0 + hi * 8]);
            bf16x8 v11 = *(const bf16x8*)(&Vc[(32 + c32) * 40 + 16 + hi * 8]);
            __builtin_amdgcn_s_setprio(1);
            oA = __builtin_amdgcn_mfma_f32_32x32x16_bf16(pa0.v, v00, oA, 0, 0, 0);
            oA = __builtin_amdgcn_mfma_f32_32x32x16_bf16(pa1.v, v10, oA, 0, 0, 0);
            oB = __builtin_amdgcn_mfma_f32_32x32x16_bf16(pa0.v, v01, oB, 0, 0, 0);
            oB = __builtin_amdgcn_mfma_f32_32x32x16_bf16(pa1.v, v11, oB, 0, 0, 0);
            __builtin_amdgcn_s_setprio(0);
        }
        if (pre) {   // LDS write after compute (vmcnt paid post-overlap)
            *(uint4*)(&Ks[nb & 1][krow * 72 + kcol])     = gK0;
            *(uint4*)(&Ks[nb & 1][krow * 72 + kcol + 8]) = gK1;
            *(uint4*)(&Vs[nb & 1][vrow * 40 + vcol])     = gV0;
            *(uint4*)(&Vs[nb & 1][vrow * 40 + vcol + 8]) = gV1;
        }
    }

    // combine halves: full l for q = q0w + c32 at every lane
    lacc += __shfl_xor(lacc, 32, 64);

    if (!is_split) {
        float inv = 1.0f / lacc;
#pragma unroll
        for (int r = 0; r < 16; r++) {
            int qr = (r & 3) + 8 * (r >> 2) + 4 * hi;   // output q-row of reg r
            float invr = __shfl(inv, qr, 64);
            int sg = q0w + qr;
            unsigned short* Ap = A + ((size_t)b * S_LEN + sg) * DMODEL + h * DKH;
            Ap[c32]      = f2bfu(oA[r] * invr);
            Ap[32 + c32] = f2bfu(oB[r] * invr);
        }
    } else {
        const int slot = bh * SLOTS_BH + (qb - SPLIT_Q0) * 2 + spl;
        float* Po = Scr + (size_t)slot * 4096;
        float* Pl = Scr + PO_FLOATS + (size_t)slot * 64;
#pragma unroll
        for (int r = 0; r < 16; r++) {
            int qr  = (r & 3) + 8 * (r >> 2) + 4 * hi;
            int row = wave * 32 + qr;
            Po[row * 64 + c32]      = oA[r];
            Po[row * 64 + 32 + c32] = oB[r];
        }
        if (hi == 0) Pl[wave * 32 + c32] = lacc;
    }
}

// ---------------------------------------------------------------------------
// Merged combine + Wo-convert: blocks [0,480) combine split partials;
// blocks [480,992) convert Wo -> bf16.
// ---------------------------------------------------------------------------
__global__ __launch_bounds__(256) void combine_cvtwo(
    const float* __restrict__ Scr, unsigned short* __restrict__ A,
    const float* __restrict__ Wo, unsigned short* __restrict__ Wob)
{
    if (blockIdx.x >= 480) {
        size_t idx = ((size_t)(blockIdx.x - 480) * 256 + threadIdx.x) * 8;
        float4 a = *(const float4*)(Wo + idx);
        float4 b = *(const float4*)(Wo + idx + 4);
        u16x8 hh;
        hh[0] = f2bfu(a.x); hh[1] = f2bfu(a.y); hh[2] = f2bfu(a.z); hh[3] = f2bfu(a.w);
        hh[4] = f2bfu(b.x); hh[5] = f2bfu(b.y); hh[6] = f2bfu(b.z); hh[7] = f2bfu(b.w);
        *(u16x8*)(Wob + idx) = hh;
        return;
    }
    const int bx  = blockIdx.x;
    const int bh  = bx / 15;
    const int qbm = bx % 15;
    const int qb  = SPLIT_Q0 + qbm;
    const int b   = bh >> 4;
    const int h   = bh & 15;

    const int slot0 = bh * SLOTS_BH + qbm * 2;
    const float* O0 = Scr + (size_t)slot0 * 4096;
    const float* O1 = O0 + 4096;
    const float* L0 = Scr + PO_FLOATS + (size_t)slot0 * 64;
    const float* L1 = L0 + 64;

    const int r  = threadIdx.x >> 2;
    const int cg = (threadIdx.x & 3) * 16;

    float inv = 1.0f / (L0[r] + L1[r]);

    u16x8 outv[2];
#pragma unroll
    for (int half = 0; half < 2; half++) {
        float4 a0 = *(const float4*)(O0 + r * 64 + cg + half * 8);
        float4 b0 = *(const float4*)(O0 + r * 64 + cg + half * 8 + 4);
        float4 a1 = *(const float4*)(O1 + r * 64 + cg + half * 8);
        float4 b1 = *(const float4*)(O1 + r * 64 + cg + half * 8 + 4);
        outv[half][0] = f2bfu((a0.x + a1.x) * inv);
        outv[half][1] = f2bfu((a0.y + a1.y) * inv);
        outv[half][2] = f2bfu((a0.z + a1.z) * inv);
        outv[half][3] = f2bfu((a0.w + a1.w) * inv);
        outv[half][4] = f2bfu((b0.x + b1.x) * inv);
        outv[half][5] = f2bfu((b0.y + b1.y) * inv);
        outv[half][6] = f2bfu((b0.z + b1.z) * inv);
        outv[half][7] = f2bfu((b0.w + b1.w) * inv);
    }
    const int s = qb * 64 + r;
    unsigned short* Ap = A + ((size_t)b * S_LEN + s) * DMODEL + h * DKH + cg;
    *(u16x8*)(Ap)     = outv[0];
    *(u16x8*)(Ap + 8) = outv[1];
}

extern "C" void kernel_launch(void* const* d_in, const int* in_sizes, int n_in,
                              void* d_out, int out_size, void* d_ws, size_t ws_size,
                              hipStream_t stream) {
    const float* x  = (const float*)d_in[0];
    const float* Wq = (const float*)d_in[1];
    const float* Wk = (const float*)d_in[2];
    const float* Wv = (const float*)d_in[3];
    const float* Wo = (const float*)d_in[4];
    float* out = (float*)d_out;

    unsigned short* Qw = (unsigned short*)d_ws;
    unsigned short* Kw = Qw + (size_t)MROWS * DMODEL;
    unsigned short* Vw = Kw + (size_t)MROWS * DMODEL;
    unsigned short* Wb = Vw + (size_t)MROWS * DMODEL;
    unsigned short* Aw = Wb;    // aliased; QKV completes before attn writes A
    unsigned short* Wob = Qw;   // aliased; Q dead after attn_mfma
    unsigned short* Xb = (unsigned short*)d_out;
    float* Scr = (float*)d_out;

    cvt_all<<<dim3(DMODEL * DMODEL / (256 * 8), 7), 256, 0, stream>>>(Wq, Wk, Wv, x, Wb, Xb);

    gemm_qkv<<<dim3(3 * DMODEL / 128, MROWS / 128), 256, 0, stream>>>(
        Xb, Wb, Qw, Kw, Vw);

    attn_mfma<<<dim3(NHEADS * BATCH, NPIECE), 128, 0, stream>>>(Qw, Kw, Vw, Aw, Scr);

    combine_cvtwo<<<dim3(480 + 512), 256, 0, stream>>>(Scr, Aw, Wo, Wob);

    gemm_wo<<<dim3(DMODEL / 128, MROWS / 64), 256, 0, stream>>>(Aw, Wob, out);
}